// Round 13
// baseline (562.504 us; speedup 1.0000x reference)
//
#include <hip/hip_runtime.h>
#include <math.h>

#define NN 16384
#define KK 16
#define RPW 4                       // rows per scan wave
#define SW 4                        // scan waves per block
#define RPB (SW * RPW)              // 16 rows per block
#define CAP 512                     // per-row candidate buffer (u16 idx)
#define P0T 8                       // pass-0 sample tiles (2048 candidates)

typedef float f32x4 __attribute__((ext_vector_type(4)));
typedef unsigned long long u64;
typedef unsigned short u16;

// ---------- pack nodes into SoA float4 {x,y,z,sq} (reference arithmetic) ----
__global__ void prep_kernel(const float* __restrict__ nodes,
                            float4* __restrict__ pts) {
#pragma clang fp contract(off)
    const int i = blockIdx.x * blockDim.x + threadIdx.x;
    if (i < NN) {
        const float x = nodes[3 * i + 0];
        const float y = nodes[3 * i + 1];
        const float z = nodes[3 * i + 2];
        pts[i] = make_float4(x, y, z, (x * x + y * y) + z * z);
    }
}

__device__ __forceinline__ float bcastf(float v, int l) {
    return __int_as_float(__builtin_amdgcn_readlane(__float_as_int(v), l));
}

// Verified dist-domain distributed top-17 insert (r1-r6). Exact lex-(dist,idx)
// semantics including sqrt-tie collapse; used on ~160 candidates per row.
__device__ __forceinline__ bool lexless(float da, int ia, float db, int ib) {
    return (da < db) || ((da == db) && (ia < ib));
}

__device__ __forceinline__ void insert_tile(bool rough, float d2, int j,
                                            float& ld, int& li,
                                            float& td, int& ti, float& td2u,
                                            int lane) {
#pragma clang fp contract(off)
    if (!__any(rough)) return;
    float dist = INFINITY;
    if (rough) dist = sqrtf(fmaxf(d2, 0.0f));   // IEEE sqrt, matches reference
    bool done = false;
    while (true) {
        const bool pass = (!done) && rough && lexless(dist, j, td, ti);
        const u64 m = __ballot(pass);
        if (m == 0ull) break;
        const int src = __ffsll(m) - 1;
        const float dc = __shfl(dist, src);
        const int   ic = __shfl(j, src);
        if (lane == src) done = true;
        const bool gt = lexless(dc, ic, ld, li);
        const u64 gm = __ballot(gt);
        const int p = __ffsll(gm) - 1;
        const float pd = __shfl_up(ld, 1);
        const int   pi = __shfl_up(li, 1);
        if (gt) {
            if (lane == p) { ld = dc; li = ic; }
            else           { ld = pd; li = pi; }
        }
        td = __shfl(ld, 16);
        ti = __shfl(li, 16);
        td2u = td * td * 1.000001f;
    }
}

// ---------- main kernel: 4 scan waves (4 rows each) + 1 zero/ones wave ------
__global__ __launch_bounds__(320) void knn_main(const float4* __restrict__ pts,
                                                float* __restrict__ out) {
#pragma clang fp contract(off)
    const int lane = threadIdx.x & 63;
    const int wid  = threadIdx.x >> 6;
    const int rowBase = blockIdx.x * RPB;

    __shared__ u16 buf[SW][RPW][CAP];   // 16 KB candidate indices
    __shared__ int cnt[SW][RPW];
    __shared__ int nb[RPB][KK];

    if (wid == SW) {
        // Fill wave: NT-stream zeros for this block's 16 rows (1 MB).
        f32x4* ob = (f32x4*)(out + (size_t)rowBase * NN);
        const f32x4 z4 = {0.f, 0.f, 0.f, 0.f};
#pragma unroll 8
        for (int k = 0; k < RPB * (NN / 4) / 64; ++k)
            __builtin_nontemporal_store(z4, ob + k * 64 + lane);
        // Drain so this wave's later 1.0 stores are ordered after the zeros.
        asm volatile("s_waitcnt vmcnt(0)" ::: "memory");
    } else {
        const int r0 = rowBase + wid * RPW;
        float xs[RPW], ys[RPW], zs[RPW], ss[RPW];
#pragma unroll
        for (int r = 0; r < RPW; ++r) {
            const float4 p = pts[r0 + r];
            xs[r] = p.x; ys[r] = p.y; zs[r] = p.z; ss[r] = p.w;
        }

        // ======= PASS 0: per-lane min of raw d2 over a 2048 sample =======
        // tau from an ACTUAL candidate subset: 17th order statistic of a
        // subset >= 17th of the full set -> conservative (r12 argument).
        float rm[RPW];
#pragma unroll
        for (int r = 0; r < RPW; ++r) rm[r] = INFINITY;
        {
            float4 q0 = pts[lane];
            float4 q1 = pts[64 + lane];
            float4 q2 = pts[128 + lane];
            float4 q3 = pts[192 + lane];
            for (int t = 0; t < P0T; ++t) {
                const int nxt = (t + 1 < P0T) ? (t + 1) * 256 : t * 256;
                const float4 n0 = pts[nxt + lane];
                const float4 n1 = pts[nxt + 64 + lane];
                const float4 n2 = pts[nxt + 128 + lane];
                const float4 n3 = pts[nxt + 192 + lane];
#pragma unroll
                for (int r = 0; r < RPW; ++r) {
                    // Reference arithmetic: fma-chain dot, un-contracted d2.
                    const float d0 = (ss[r] + q0.w) - 2.0f * fmaf(zs[r], q0.z, fmaf(ys[r], q0.y, xs[r] * q0.x));
                    const float d1 = (ss[r] + q1.w) - 2.0f * fmaf(zs[r], q1.z, fmaf(ys[r], q1.y, xs[r] * q1.x));
                    const float d2 = (ss[r] + q2.w) - 2.0f * fmaf(zs[r], q2.z, fmaf(ys[r], q2.y, xs[r] * q2.x));
                    const float d3 = (ss[r] + q3.w) - 2.0f * fmaf(zs[r], q3.z, fmaf(ys[r], q3.y, xs[r] * q3.x));
                    rm[r] = fminf(rm[r], fminf(fminf(d0, d1), fminf(d2, d3)));
                }
                q0 = n0; q1 = n1; q2 = n2; q3 = n3;
            }
        }

        // ====== bitonic sort of 64 lane-mins (r12-verified); tau = 17th ======
        float sv[RPW];
#pragma unroll
        for (int r = 0; r < RPW; ++r) sv[r] = rm[r];
#pragma unroll
        for (int k = 2; k <= 64; k <<= 1) {
#pragma unroll
            for (int j = k >> 1; j >= 1; j >>= 1) {
                const bool keepmin = (((lane & j) == 0) == ((lane & k) == 0));
#pragma unroll
                for (int r = 0; r < RPW; ++r) {
                    const float o = __shfl_xor(sv[r], j);
                    sv[r] = keepmin ? fminf(sv[r], o) : fmaxf(sv[r], o);
                }
            }
        }
        float tau[RPW];
#pragma unroll
        for (int r = 0; r < RPW; ++r)   // *1.000002+eps: sqrt-tie-collapse guard
            tau[r] = fmaxf(bcastf(sv[r], 16), 0.0f) * 1.000002f + 1e-30f;

        if (lane < RPW) cnt[wid][lane] = 0;
        asm volatile("s_waitcnt lgkmcnt(0)" ::: "memory");

        // ======== PASS B (only full pass): screen vs tau, append u16 ========
        {
            float4 q0 = pts[lane];
            float4 q1 = pts[64 + lane];
            float4 q2 = pts[128 + lane];
            float4 q3 = pts[192 + lane];
            for (int t = 0; t < NN / 256; ++t) {
                const int base = t * 256;
                const int nxt = (t + 1 < NN / 256) ? base + 256 : base;
                const float4 n0 = pts[nxt + lane];
                const float4 n1 = pts[nxt + 64 + lane];
                const float4 n2 = pts[nxt + 128 + lane];
                const float4 n3 = pts[nxt + 192 + lane];
#pragma unroll
                for (int r = 0; r < RPW; ++r) {
                    const float d0 = (ss[r] + q0.w) - 2.0f * fmaf(zs[r], q0.z, fmaf(ys[r], q0.y, xs[r] * q0.x));
                    const float d1 = (ss[r] + q1.w) - 2.0f * fmaf(zs[r], q1.z, fmaf(ys[r], q1.y, xs[r] * q1.x));
                    const float d2 = (ss[r] + q2.w) - 2.0f * fmaf(zs[r], q2.z, fmaf(ys[r], q2.y, xs[r] * q2.x));
                    const float d3 = (ss[r] + q3.w) - 2.0f * fmaf(zs[r], q3.z, fmaf(ys[r], q3.y, xs[r] * q3.x));
                    const bool p0 = d0 <= tau[r], p1 = d1 <= tau[r];
                    const bool p2 = d2 <= tau[r], p3 = d3 <= tau[r];
                    if (p0 | p1 | p2 | p3) {
                        if (p0) { const int o = atomicAdd(&cnt[wid][r], 1);
                                  if (o < CAP) buf[wid][r][o] = (u16)(base + lane); }
                        if (p1) { const int o = atomicAdd(&cnt[wid][r], 1);
                                  if (o < CAP) buf[wid][r][o] = (u16)(base + 64 + lane); }
                        if (p2) { const int o = atomicAdd(&cnt[wid][r], 1);
                                  if (o < CAP) buf[wid][r][o] = (u16)(base + 128 + lane); }
                        if (p3) { const int o = atomicAdd(&cnt[wid][r], 1);
                                  if (o < CAP) buf[wid][r][o] = (u16)(base + 192 + lane); }
                    }
                }
                q0 = n0; q1 = n1; q2 = n2; q3 = n3;
            }
        }
        asm volatile("s_waitcnt lgkmcnt(0)" ::: "memory");

        // ===== SELECT: exact top-17 via verified dist-domain insert over C =====
#pragma unroll
        for (int r = 0; r < RPW; ++r) {
            const int C = cnt[wid][r];          // wave-uniform broadcast read
            const int rowl = wid * RPW + r;
            if (C <= CAP) {                     // C >= 17 guaranteed by tau
                float ld = INFINITY; int li = 0x7fffffff;
                float td = INFINITY; int ti = 0x7fffffff; float t2 = INFINITY;
                const int ntiles = (C + 63) >> 6;
                for (int tt = 0; tt < ntiles; ++tt) {
                    const int s = tt * 64 + lane;
                    const bool valid = (s < C);
                    const int idx = valid ? (int)buf[wid][r][s] : 0;
                    const float4 q = pts[idx];
                    const float dd = (ss[r] + q.w) - 2.0f * fmaf(zs[r], q.z, fmaf(ys[r], q.y, xs[r] * q.x));
                    insert_tile(valid && (dd <= t2), dd, idx, ld, li, td, ti, t2, lane);
                }
                if (lane >= 1 && lane <= KK) nb[rowl][lane - 1] = li;
            } else {
                // Pathological overflow: verified full-scan insert for this row.
                float ld = INFINITY; int li = 0x7fffffff;
                float td = INFINITY; int ti = 0x7fffffff; float t2 = INFINITY;
                for (int tt = 0; tt < NN / 64; ++tt) {
                    const int j = tt * 64 + lane;
                    const float4 q = pts[j];
                    const float dd = (ss[r] + q.w) - 2.0f * fmaf(zs[r], q.z, fmaf(ys[r], q.y, xs[r] * q.x));
                    insert_tile(dd <= t2, dd, j, ld, li, td, ti, t2, lane);
                }
                if (lane >= 1 && lane <= KK) nb[rowl][lane - 1] = li;
            }
        }
    }

    __syncthreads();

    // Fill wave writes all 256 ones (16 rows x 16), ordered after its own
    // drained zero stores (same-wave ordering, r6/r12-verified pattern).
    if (wid == SW) {
#pragma unroll
        for (int m = lane; m < RPB * KK; m += 64) {
            const int r = m >> 4;
            out[(size_t)(rowBase + r) * NN + nb[r][m & 15]] = 1.0f;
        }
    }
}

extern "C" void kernel_launch(void* const* d_in, const int* in_sizes, int n_in,
                              void* d_out, int out_size, void* d_ws, size_t ws_size,
                              hipStream_t stream) {
    const float* nodes = (const float*)d_in[0];
    float* out = (float*)d_out;
    (void)in_sizes; (void)n_in; (void)out_size; (void)ws_size;
    float4* pts = (float4*)d_ws;    // 256 KB scratch

    hipLaunchKernelGGL(prep_kernel, dim3(NN / 256), dim3(256), 0, stream,
                       nodes, pts);
    hipLaunchKernelGGL(knn_main, dim3(NN / RPB), dim3(320), 0, stream,
                       pts, out);
}

// Round 14
// 339.359 us; speedup vs baseline: 1.6575x; 1.6575x over previous
//
#include <hip/hip_runtime.h>
#include <math.h>

#define NN 16384
#define KK 16
#define RPW 4                       // rows per scan wave
#define SW 4                        // scan waves per block
#define RPB (SW * RPW)              // 16 rows per block
#define CAP 128                     // per-row candidate buffer
#define P0T 32                      // pass-0 sample tiles (8192 candidates, s=128/lane)

typedef float f32x4 __attribute__((ext_vector_type(4)));
typedef unsigned long long u64;

// ---------- pack nodes into SoA float4 {x,y,z,sq} (reference arithmetic) ----
__global__ void prep_kernel(const float* __restrict__ nodes,
                            float4* __restrict__ pts) {
#pragma clang fp contract(off)
    const int i = blockIdx.x * blockDim.x + threadIdx.x;
    if (i < NN) {
        const float x = nodes[3 * i + 0];
        const float y = nodes[3 * i + 1];
        const float z = nodes[3 * i + 2];
        pts[i] = make_float4(x, y, z, (x * x + y * y) + z * z);
    }
}

__device__ __forceinline__ float bcastf(float v, int l) {
    return __int_as_float(__builtin_amdgcn_readlane(__float_as_int(v), l));
}

// Verified distributed-sorted-list insert (r1-r6) — overflow fallback only.
__device__ __forceinline__ bool lexless(float da, int ia, float db, int ib) {
    return (da < db) || ((da == db) && (ia < ib));
}

__device__ __forceinline__ void insert_tile(bool rough, float d2, int j,
                                            float& ld, int& li,
                                            float& td, int& ti, float& td2u,
                                            int lane) {
#pragma clang fp contract(off)
    if (!__any(rough)) return;
    float dist = INFINITY;
    if (rough) dist = sqrtf(fmaxf(d2, 0.0f));
    bool done = false;
    while (true) {
        const bool pass = (!done) && rough && lexless(dist, j, td, ti);
        const u64 m = __ballot(pass);
        if (m == 0ull) break;
        const int src = __ffsll(m) - 1;
        const float dc = __shfl(dist, src);
        const int   ic = __shfl(j, src);
        if (lane == src) done = true;
        const bool gt = lexless(dc, ic, ld, li);
        const u64 gm = __ballot(gt);
        const int p = __ffsll(gm) - 1;
        const float pd = __shfl_up(ld, 1);
        const int   pi = __shfl_up(li, 1);
        if (gt) {
            if (lane == p) { ld = dc; li = ic; }
            else           { ld = pd; li = pi; }
        }
        td = __shfl(ld, 16);
        ti = __shfl(li, 16);
        td2u = td * td * 1.000001f;
    }
}

// ---------- main kernel: 4 scan waves (4 rows each) + 1 zero/ones wave ------
__global__ __launch_bounds__(320) void knn_main(const float4* __restrict__ pts,
                                                float* __restrict__ out) {
#pragma clang fp contract(off)
    const int lane = threadIdx.x & 63;
    const int wid  = threadIdx.x >> 6;
    const int rowBase = blockIdx.x * RPB;

    __shared__ u64 buf[SW][RPW][CAP];   // 16 KB candidate keys (cd2, idx)
    __shared__ int cnt[SW][RPW];
    __shared__ int nb[RPB][KK];

    if (wid == SW) {
        // Fill wave: NT-stream zeros for this block's 16 rows (1 MB).
        f32x4* ob = (f32x4*)(out + (size_t)rowBase * NN);
        const f32x4 z4 = {0.f, 0.f, 0.f, 0.f};
#pragma unroll 8
        for (int k = 0; k < RPB * (NN / 4) / 64; ++k)
            __builtin_nontemporal_store(z4, ob + k * 64 + lane);
        // Drain so this wave's later 1.0 stores are ordered after the zeros.
        asm volatile("s_waitcnt vmcnt(0)" ::: "memory");
    } else {
        const int r0 = rowBase + wid * RPW;
        float xs[RPW], ys[RPW], zs[RPW], ss[RPW];
#pragma unroll
        for (int r = 0; r < RPW; ++r) {
            const float4 p = pts[r0 + r];
            xs[r] = p.x; ys[r] = p.y; zs[r] = p.z; ss[r] = p.w;
        }

        // ==== PASS A (sampled): per-lane min of raw d2 over 32 tiles ====
        // tau from an ACTUAL candidate subset: 17th order statistic of a
        // subset >= 17th of the full set -> conservative (r12/r13 argument).
        // s=128 samples/lane -> E[survivors] ~ 34, well under CAP.
        float rm[RPW];
#pragma unroll
        for (int r = 0; r < RPW; ++r) rm[r] = INFINITY;
        {
            float4 q0 = pts[lane];
            float4 q1 = pts[64 + lane];
            float4 q2 = pts[128 + lane];
            float4 q3 = pts[192 + lane];
            for (int t = 0; t < P0T; ++t) {
                const int nxt = (t + 1 < P0T) ? (t + 1) * 256 : t * 256;
                const float4 n0 = pts[nxt + lane];
                const float4 n1 = pts[nxt + 64 + lane];
                const float4 n2 = pts[nxt + 128 + lane];
                const float4 n3 = pts[nxt + 192 + lane];
#pragma unroll
                for (int r = 0; r < RPW; ++r) {
                    // Reference arithmetic: fma-chain dot, un-contracted d2.
                    const float d0 = (ss[r] + q0.w) - 2.0f * fmaf(zs[r], q0.z, fmaf(ys[r], q0.y, xs[r] * q0.x));
                    const float d1 = (ss[r] + q1.w) - 2.0f * fmaf(zs[r], q1.z, fmaf(ys[r], q1.y, xs[r] * q1.x));
                    const float d2 = (ss[r] + q2.w) - 2.0f * fmaf(zs[r], q2.z, fmaf(ys[r], q2.y, xs[r] * q2.x));
                    const float d3 = (ss[r] + q3.w) - 2.0f * fmaf(zs[r], q3.z, fmaf(ys[r], q3.y, xs[r] * q3.x));
                    rm[r] = fminf(rm[r], fminf(fminf(d0, d1), fminf(d2, d3)));
                }
                q0 = n0; q1 = n1; q2 = n2; q3 = n3;
            }
        }

        // ====== bitonic sort of 64 lane-mins (r12-verified); tau = 17th ======
        float sv[RPW];
#pragma unroll
        for (int r = 0; r < RPW; ++r) sv[r] = rm[r];
#pragma unroll
        for (int k = 2; k <= 64; k <<= 1) {
#pragma unroll
            for (int j = k >> 1; j >= 1; j >>= 1) {
                const bool keepmin = (((lane & j) == 0) == ((lane & k) == 0));
#pragma unroll
                for (int r = 0; r < RPW; ++r) {
                    const float o = __shfl_xor(sv[r], j);
                    sv[r] = keepmin ? fminf(sv[r], o) : fmaxf(sv[r], o);
                }
            }
        }
        float tau[RPW];
#pragma unroll
        for (int r = 0; r < RPW; ++r)   // *1.000002+eps: sqrt-tie-collapse guard
            tau[r] = fmaxf(bcastf(sv[r], 16), 0.0f) * 1.000002f + 1e-30f;

        if (lane < RPW) cnt[wid][lane] = 0;
        asm volatile("s_waitcnt lgkmcnt(0)" ::: "memory");

        // ============ PASS B: screen vs fixed tau, atomic append ============
        {
            float4 q0 = pts[lane];
            float4 q1 = pts[64 + lane];
            float4 q2 = pts[128 + lane];
            float4 q3 = pts[192 + lane];
            for (int t = 0; t < NN / 256; ++t) {
                const int base = t * 256;
                const int nxt = (t + 1 < NN / 256) ? base + 256 : base;
                const float4 n0 = pts[nxt + lane];
                const float4 n1 = pts[nxt + 64 + lane];
                const float4 n2 = pts[nxt + 128 + lane];
                const float4 n3 = pts[nxt + 192 + lane];
#pragma unroll
                for (int r = 0; r < RPW; ++r) {
                    const float d0 = (ss[r] + q0.w) - 2.0f * fmaf(zs[r], q0.z, fmaf(ys[r], q0.y, xs[r] * q0.x));
                    const float d1 = (ss[r] + q1.w) - 2.0f * fmaf(zs[r], q1.z, fmaf(ys[r], q1.y, xs[r] * q1.x));
                    const float d2 = (ss[r] + q2.w) - 2.0f * fmaf(zs[r], q2.z, fmaf(ys[r], q2.y, xs[r] * q2.x));
                    const float d3 = (ss[r] + q3.w) - 2.0f * fmaf(zs[r], q3.z, fmaf(ys[r], q3.y, xs[r] * q3.x));
                    const bool p0 = d0 <= tau[r], p1 = d1 <= tau[r];
                    const bool p2 = d2 <= tau[r], p3 = d3 <= tau[r];
                    if (p0 | p1 | p2 | p3) {
                        if (p0) { const int o = atomicAdd(&cnt[wid][r], 1);
                                  if (o < CAP) buf[wid][r][o] = (((u64)__float_as_uint(fmaxf(d0, 0.f))) << 32) | (unsigned)(base + lane); }
                        if (p1) { const int o = atomicAdd(&cnt[wid][r], 1);
                                  if (o < CAP) buf[wid][r][o] = (((u64)__float_as_uint(fmaxf(d1, 0.f))) << 32) | (unsigned)(base + 64 + lane); }
                        if (p2) { const int o = atomicAdd(&cnt[wid][r], 1);
                                  if (o < CAP) buf[wid][r][o] = (((u64)__float_as_uint(fmaxf(d2, 0.f))) << 32) | (unsigned)(base + 128 + lane); }
                        if (p3) { const int o = atomicAdd(&cnt[wid][r], 1);
                                  if (o < CAP) buf[wid][r][o] = (((u64)__float_as_uint(fmaxf(d3, 0.f))) << 32) | (unsigned)(base + 192 + lane); }
                    }
                }
                q0 = n0; q1 = n1; q2 = n2; q3 = n3;
            }
        }
        asm volatile("s_waitcnt lgkmcnt(0)" ::: "memory");

        // ============ exact lex-(dist,idx) rank among C candidates ============
#pragma unroll
        for (int r = 0; r < RPW; ++r) {
            const int C = cnt[wid][r];          // wave-uniform
            const int rowl = wid * RPW + r;
            if (C <= CAP) {                     // C >= 17 guaranteed by tau
                for (int e = lane; e < C; e += 64) {
                    const u64 k2 = buf[wid][r][e];
                    const float dd = sqrtf(__uint_as_float((unsigned)(k2 >> 32)));
                    buf[wid][r][e] = (((u64)__float_as_uint(dd)) << 32) | (k2 & 0xffffffffull);
                }
                asm volatile("s_waitcnt lgkmcnt(0)" ::: "memory");
                for (int e = lane; e < C; e += 64) {
                    const u64 my = buf[wid][r][e];
                    int rk = 0;
                    for (int c = 0; c < C; ++c)
                        rk += (buf[wid][r][c] < my) ? 1 : 0;   // idx unique => no key ties
                    if (rk >= 1 && rk <= KK)
                        nb[rowl][rk - 1] = (int)(my & 0xffffffffu);  // rank 0 = lex-min, dropped
                }
            } else {
                // Pathological overflow: verified streaming insert for this row.
                float ld = INFINITY; int li = 0x7fffffff;
                float td = INFINITY; int ti = 0x7fffffff; float t2 = INFINITY;
                for (int tt = 0; tt < NN / 64; ++tt) {
                    const int j = tt * 64 + lane;
                    const float4 q = pts[j];
                    const float dd = (ss[r] + q.w) - 2.0f * fmaf(zs[r], q.z, fmaf(ys[r], q.y, xs[r] * q.x));
                    insert_tile(dd <= t2, dd, j, ld, li, td, ti, t2, lane);
                }
                if (lane >= 1 && lane <= KK) nb[rowl][lane - 1] = li;
            }
        }
    }

    __syncthreads();

    // Fill wave writes all 256 ones (16 rows x 16), ordered after its own
    // drained zero stores (same-wave ordering, r6/r12-verified pattern).
    if (wid == SW) {
#pragma unroll
        for (int m = lane; m < RPB * KK; m += 64) {
            const int r = m >> 4;
            out[(size_t)(rowBase + r) * NN + nb[r][m & 15]] = 1.0f;
        }
    }
}

extern "C" void kernel_launch(void* const* d_in, const int* in_sizes, int n_in,
                              void* d_out, int out_size, void* d_ws, size_t ws_size,
                              hipStream_t stream) {
    const float* nodes = (const float*)d_in[0];
    float* out = (float*)d_out;
    (void)in_sizes; (void)n_in; (void)out_size; (void)ws_size;
    float4* pts = (float4*)d_ws;    // 256 KB scratch

    hipLaunchKernelGGL(prep_kernel, dim3(NN / 256), dim3(256), 0, stream,
                       nodes, pts);
    hipLaunchKernelGGL(knn_main, dim3(NN / RPB), dim3(320), 0, stream,
                       pts, out);
}